// Round 6
// baseline (1042.873 us; speedup 1.0000x reference)
//
#include <hip/hip_runtime.h>
#include <hip/hip_bf16.h>

#define NT 1024
#define NNODES 4096
#define ECAP 65536   // max arcs after iteration-1 symmetrization (E0 <= 32768)

// ---------------- grid-parallel 2MB bitmap zero (replaces hipMemsetAsync) ----------------
__global__ __launch_bounds__(256)
void zeroBM(int4* __restrict__ bm) {
    bm[(size_t)blockIdx.x * 256 + threadIdx.x] = make_int4(0, 0, 0, 0);
}

// ---------------- block-wide exclusive scan over NT=1024 values ----------------
__device__ __forceinline__ int blockScanExcl(int v, int* s_w, int* total) {
    const int tid  = threadIdx.x;
    const int lane = tid & 63;
    const int wv   = tid >> 6;
    int x = v;
#pragma unroll
    for (int off = 1; off < 64; off <<= 1) {
        int t = __shfl_up(x, off, 64);
        if (lane >= off) x += t;
    }
    if (lane == 63) s_w[wv] = x;
    __syncthreads();
    if (tid < 16) {
        int y = s_w[tid];
#pragma unroll
        for (int off = 1; off < 16; off <<= 1) {
            int t = __shfl_up(y, off, 16);
            if (tid >= off) y += t;
        }
        s_w[tid] = y;
    }
    __syncthreads();
    int base = wv ? s_w[wv - 1] : 0;
    int tot  = s_w[15];
    __syncthreads();   // protect s_w reuse
    *total = tot;
    return base + x - v;   // exclusive prefix
}

// ================= Phase A1: preamble (R4-exact), dump handoff state =================
// s_bc slots: 0=node 2=nbrCnt 4=orderBase 5=appendBase 7=maxdeg 9=not64
__global__ __launch_bounds__(NT, 1)
void phaseA1(const int* __restrict__ ei, int E0,
             int* __restrict__ U, int* __restrict__ V,
             unsigned int* __restrict__ BM,
             int* __restrict__ NBR, int* __restrict__ OTH,
             int* __restrict__ ORDV, int* __restrict__ ROFFG, int* __restrict__ RENDG,
             int* __restrict__ HAND)
{
    __shared__ unsigned short s_order[NNODES];
    __shared__ unsigned char  s_vis[NNODES];
    __shared__ unsigned char  s_rank[NNODES];     // counting-sort within-group rank
    __shared__ unsigned int   s_hb[NNODES / 32];
    __shared__ int s_roff[NNODES];
    __shared__ int s_rend[NNODES];
    __shared__ int s_tmp[NNODES];
    __shared__ int s_mat[64][65];                 // [deg][group] counts / prefixes; col 64 = desc base
    __shared__ int s_w[16];
    __shared__ int s_bc[16];

    const int tid = threadIdx.x;

    for (int i = tid; i < NNODES; i += NT) { s_vis[i] = 0; s_tmp[i] = 0; }
    for (int i = tid; i < NNODES / 32; i += NT) s_hb[i] = 0;
    if (tid < 16) s_bc[tid] = 0;
    __syncthreads();

    // ---- detect int64 vs int32 edge buffer ----
    for (int i = tid; i < E0; i += NT)
        if (ei[2 * i + 1] != 0) s_bc[9] = 1;
    __syncthreads();
    const int is64 = !s_bc[9];

    // ---- copy edges + degree histogram (I+O) ----
    for (int e = tid; e < E0; e += NT) {
        int uu = ei[is64 ? 2 * e : e];
        int vv = ei[is64 ? 2 * (E0 + e) : (E0 + e)];
        U[e] = uu; V[e] = vv;
        atomicAdd(&s_tmp[uu], 1);
        atomicAdd(&s_tmp[vv], 1);
    }
    __syncthreads();
    for (int n = tid; n < NNODES; n += NT) atomicMax(&s_bc[7], s_tmp[n]);
    __syncthreads();
    const int maxd = s_bc[7];

    // ---- stable argsort by descending degree ----
    if (maxd < 64) {
        // fast path: stable counting sort, ~5 barriers total.
        const int wv = tid >> 6, lane = tid & 63;
        const unsigned long long ltm = (1ull << lane) - 1ull;
        for (int g = wv; g < 64; g += 16) {
            int n = g * 64 + lane;
            int d = s_tmp[n];
            int rk = 0;
            for (int dd = 0; dd < 64; ++dd) {
                unsigned long long bal = __ballot(d == dd);
                if (lane == 0) s_mat[dd][g] = __popcll(bal);
                if (d == dd) rk = __popcll(bal & ltm);
            }
            s_rank[n] = (unsigned char)rk;
        }
        __syncthreads();
        if (tid < 64) {                      // per-degree prefix across the 64 id-groups
            int run = 0;
            for (int g = 0; g < 64; ++g) { int t = s_mat[tid][g]; s_mat[tid][g] = run; run += t; }
            s_mat[tid][64] = run;            // total per degree
        }
        __syncthreads();
        if (tid < 64) {                      // descending-degree exclusive base
            int x = s_mat[tid][64];
#pragma unroll
            for (int off = 1; off < 64; off <<= 1) {
                int t = __shfl_up(x, off, 64);
                if (tid >= off) x += t;
            }
            int T = __shfl(x, 63, 64);
            s_mat[tid][64] = T - x;          // sum of bins with degree > tid
        }
        __syncthreads();
        for (int g = wv; g < 64; g += 16) {
            int n = g * 64 + lane;
            int d = s_tmp[n];
            int pos = s_mat[d][64] + s_mat[d][g] + (int)s_rank[n];
            s_order[pos] = (unsigned short)n;
        }
        __syncthreads();
    } else {
        // legacy fallback (exact, slow): one scan round per degree value
        for (int d = maxd; d >= 0; --d) {
            int n0 = tid * 4;
            int f0 = (s_tmp[n0] == d), f1 = (s_tmp[n0 + 1] == d);
            int f2 = (s_tmp[n0 + 2] == d), f3 = (s_tmp[n0 + 3] == d);
            int tot;
            int off = blockScanExcl(f0 + f1 + f2 + f3, s_w, &tot);
            int idx = s_bc[4] + off;
            if (f0) s_order[idx++] = (unsigned short)n0;
            if (f1) s_order[idx++] = (unsigned short)(n0 + 1);
            if (f2) s_order[idx++] = (unsigned short)(n0 + 2);
            if (f3) s_order[idx++] = (unsigned short)(n0 + 3);
            __syncthreads();
            if (tid == 0) s_bc[4] += tot;
            __syncthreads();
        }
    }

    // ---- iteration 0 (full-array scans, eager relabel) ----
    if (tid == 0) {
        int nd = s_order[0];
        s_bc[0] = nd; s_vis[nd] = 1;
    }
    __syncthreads();
    {
        const int node = s_bc[0];
        for (int e = tid; e < E0; e += NT) {
            int uu = U[e], vv = V[e];
            if (uu == node) {
                int w = vv; unsigned m = 1u << (w & 31);
                unsigned old = atomicOr(&s_hb[w >> 5], m);
                if (!(old & m)) { int i = atomicAdd(&s_bc[2], 1); s_tmp[i] = w; s_vis[w] = 1; }
            }
            if (vv == node) {
                int w = uu; unsigned m = 1u << (w & 31);
                unsigned old = atomicOr(&s_hb[w >> 5], m);
                if (!(old & m)) { int i = atomicAdd(&s_bc[2], 1); s_tmp[i] = w; s_vis[w] = 1; }
            }
        }
        __syncthreads();
        // eager relabel Hn = H \ {node} (U/V frozen afterwards)
        for (int e = tid; e < E0; e += NT) {
            int uu = U[e];
            if (uu != node && ((s_hb[uu >> 5] >> (uu & 31)) & 1)) U[e] = node;
            int vv = V[e];
            if (vv != node && ((s_hb[vv >> 5] >> (vv & 31)) & 1)) V[e] = node;
        }
        __syncthreads();
    }

    // ---- symmetry append (only iteration ever needing it) ----
    // BM is pre-zeroed by the grid-parallel zeroBM kernel on the stream.
    for (int e = tid; e < E0; e += NT) {
        int uu = U[e], vv = V[e];
        if (uu != vv) {
            unsigned code = ((unsigned)uu << 12) | (unsigned)vv;
            atomicOr(&BM[code >> 5], 1u << (code & 31));
        }
    }
    __syncthreads();
    // single-pass ordered compaction: 32 arcs/thread bitmask + one block scan per 32K chunk
    for (int t0 = 0; t0 < E0; t0 += NT * 32) {
        unsigned fm = 0u;
        const int base = t0 + tid * 32;
        for (int j = 0; j < 32; ++j) {
            int e = base + j;
            if (e < E0) {
                int uu = U[e], vv = V[e];
                if (uu != vv) {
                    unsigned rc = ((unsigned)vv << 12) | (unsigned)uu;
                    unsigned old = atomicOr(&BM[rc >> 5], 0u);   // L2 read
                    if (!((old >> (rc & 31)) & 1u)) fm |= (1u << j);
                }
            }
        }
        int tot;
        int off = blockScanExcl(__popc(fm), s_w, &tot);
        int r = s_bc[5] + off;
        unsigned m = fm;
        while (m) {
            int j = __ffs((int)m) - 1; m &= m - 1;
            int e = base + j;
            U[E0 + r] = V[e]; V[E0 + r] = U[e];
            ++r;
        }
        __syncthreads();
        if (tid == 0) s_bc[5] += tot;
        __syncthreads();
    }
    const int E1 = E0 + s_bc[5];

    // ---- build static CSR, OUT-endpoint only ----
    for (int n = tid; n < NNODES; n += NT) s_roff[n] = 0;
    __syncthreads();
    for (int e = tid; e < E1; e += NT) {
        int uu = U[e], vv = V[e];
        if (uu != vv) atomicAdd(&s_roff[uu], 1);
    }
    __syncthreads();
    {
        int n0 = tid * 4;
        int c0 = s_roff[n0], c1 = s_roff[n0 + 1], c2 = s_roff[n0 + 2], c3 = s_roff[n0 + 3];
        int tot;
        int off = blockScanExcl(c0 + c1 + c2 + c3, s_w, &tot);
        int st = off;
        s_roff[n0] = st;     s_rend[n0] = st;     st += c0;
        s_roff[n0 + 1] = st; s_rend[n0 + 1] = st; st += c1;
        s_roff[n0 + 2] = st; s_rend[n0 + 2] = st; st += c2;
        s_roff[n0 + 3] = st; s_rend[n0 + 3] = st;
    }
    __syncthreads();
    for (int e = tid; e < E1; e += NT) {
        int uu = U[e], vv = V[e];
        if (uu != vv) {
            int p = atomicAdd(&s_rend[uu], 1);
            OTH[p] = vv;
        }
    }
    __syncthreads();
    {   // flush iter-0 staged H into global NBR
        const int cnt0 = s_bc[2];
        for (int i = tid; i < cnt0; i += NT) NBR[i] = s_tmp[i];
    }
    // ---- dump handoff state ----
    for (int i = tid; i < NNODES; i += NT) {
        int nd = (int)s_order[i];
        ORDV[i]  = nd | (s_vis[nd] ? 0x8000 : 0);
        ROFFG[i] = s_roff[i];
        RENDG[i] = s_rend[i];
    }
    if (tid == 0) { HAND[0] = E1; HAND[1] = s_bc[2]; HAND[2] = s_bc[0]; }
}

// ================= Phase A2: main loop, SINGLE WAVE, zero barriers =================
// OCTET (8-wide) processing + cross-octet prefetch + fused meta + plain-store dedup.
//   s_meta[node] = (order_slot(label) << 16) | (sel(label) ? 0x8000 : 0) | label
// Pipeline: octet n+1's candidates are extracted, premarked, and their CSR rows +
// OTH first-chunks ISSUED at octet n's start — latency hides under octet n's procs.
// Staleness (octet n absorbing a prefetched candidate) is caught by the fresh
// per-candidate check (s_meta[c] & 0x7FFF) != c right before its proc (absorption
// <=> relabel; relabels only target selected hubs, never candidates). Premark at
// prefetch keeps extraction monotone => exact reference selection order.
// All octet state in NAMED registers (runtime-indexed arrays would go to scratch).
__global__ __launch_bounds__(64, 1)
void phaseA2(const int* __restrict__ OTH, int* __restrict__ NBR,
             const int* __restrict__ ORDV, const int* __restrict__ ROFFG,
             const int* __restrict__ RENDG, const int* __restrict__ HAND,
             int* __restrict__ SEL, int* __restrict__ CNTS,
             int* __restrict__ NST, int* __restrict__ FIL, int* __restrict__ SC,
             int* __restrict__ LABG, int* __restrict__ RNKG)
{
    __shared__ unsigned short s_ord[NNODES];          // order slot -> node id
    __shared__ unsigned int   s_visbits[NNODES / 32]; // visited bit per ORDER SLOT
    __shared__ unsigned int   s_meta[NNODES];         // fused label/slot/sel word
    __shared__ unsigned short s_so[NNODES];           // selection order of hubs
    __shared__ int s_cnt[NNODES];                     // per-iteration |H_k|
    __shared__ int s_stamp[NNODES];                   // dedup scratch; reused as rank
    __shared__ int s_roff[NNODES];
    __shared__ int s_rend[NNODES];

    const int ln = threadIdx.x;                   // single wave: tid == lane
    const unsigned long long ltm = (1ull << ln) - 1ull;
    const int cnt0 = HAND[1], hub0 = HAND[2];
    volatile int* vstamp = s_stamp;               // blocks store->load forwarding

    for (int i = ln; i < NNODES / 32; i += 64) s_visbits[i] = 0u;
    for (int i = ln; i < NNODES; i += 64) {
        int ov = ORDV[i];
        int nd = ov & 0x7FFF;
        s_ord[i] = (unsigned short)nd;
        s_meta[nd] = ((unsigned)i << 16) | (unsigned)nd;   // slot | id, unselected
        s_roff[i] = ROFFG[i];
        s_rend[i] = RENDG[i];
        s_stamp[i] = 0; s_cnt[i] = 0;
        if (ov & 0x8000) atomicOr(&s_visbits[i >> 5], 1u << (i & 31));
    }
    if (ln == 0) {
        // hub0 is order-slot 0 (highest degree): meta = (0<<16)|hub0|selbit
        s_meta[hub0] = (unsigned)hub0 | 0x8000u;
        s_so[0] = (unsigned short)hub0;
        s_cnt[0] = cnt0;
    }
    // single wave: instruction order + lgkmcnt waits give LDS visibility; no barrier.

    int nc = cnt0;   // NBR cursor, wave-uniform register
    int k = 1;

    // register-resident bitmask extraction: lane ln holds words {ln, ln+64}
    unsigned lo = 0u, hi = 0u;
    auto extract = [&]() -> int {
        unsigned long long b = __ballot(lo != 0u);
        if (b) {
            int sl = __ffsll((long long)b) - 1;
            unsigned ww = __shfl(lo, sl, 64);
            if (ln == sl) lo &= lo - 1;
            return sl * 32 + (__ffs((int)ww) - 1);
        }
        b = __ballot(hi != 0u);
        if (b) {
            int sl = __ffsll((long long)b) - 1;
            unsigned ww = __shfl(hi, sl, 64);
            if (ln == sl) hi &= hi - 1;
            return 2048 + sl * 32 + (__ffs((int)ww) - 1);
        }
        return -1;
    };

    // common commit for newly-found H members (bal already computed)
    auto commitNew = [&](unsigned g, int w, bool nw, unsigned long long bal,
                         unsigned relv) {
        if (nw) {
            NBR[nc + __popcll(bal & ltm)] = w;       // fire-and-forget
            int slot = (int)(g >> 16);               // slot(w) from the gather
            atomicOr(&s_visbits[slot >> 5], 1u << (slot & 31));
            if (!(g & 0x8000u)) s_meta[w] = relv;    // relabel unselected w
        }
        nc += __popcll(bal);
    };

    // fast proc: single chunk (re-rb <= 64), g pre-gathered for lane's o
    auto procFast = [&](int hub, int hslot, int o, unsigned g) {
        const unsigned relv = ((unsigned)hslot << 16) | (unsigned)hub | 0x8000u;
        int w = (o >= 0) ? (int)(g & 0x7FFFu) : hub;
        bool valid = (o >= 0) && (w != hub);
        if (valid) vstamp[w] = ln;                   // plain store (one winner/addr)
        int r = valid ? vstamp[w] : -1;              // in-order LDS read-back
        bool nw = valid && (r == ln);
        unsigned long long bal = __ballot(nw);
        commitNew(g, w, nw, bal, relv);
    };

    // slow proc: multi-chunk row, epoch atomicMax dedup with key k<<6
    // (fast-path lane-id residues < 64 <= k<<6 can never alias an epoch)
    auto procSlow = [&](int hub, int hslot, int rb, int re, int o0) {
        const unsigned relv = ((unsigned)hslot << 16) | (unsigned)hub | 0x8000u;
        const int key = k << 6;
        int o = o0;
        for (int s0 = rb; s0 < re; s0 += 64) {
            unsigned g = (o >= 0) ? s_meta[o] : 0u;
            int w = (o >= 0) ? (int)(g & 0x7FFFu) : hub;
            bool cnd = (w != hub);
            int old = key;
            if (cnd) old = atomicMax(&s_stamp[w], key);
            bool nw = cnd && (old < key);
            unsigned long long bal = __ballot(nw);
            commitNew(g, w, nw, bal, relv);
            int s1 = s0 + 64;
            o = (s1 + ln < re) ? OTH[s1 + ln] : -1;
        }
    };

    // ---- named octet prefetch state ----
    int nsl0=-1,nsl1=-1,nsl2=-1,nsl3=-1,nsl4=-1,nsl5=-1,nsl6=-1,nsl7=-1;
    int ncd0=-1,ncd1=-1,ncd2=-1,ncd3=-1,ncd4=-1,ncd5=-1,ncd6=-1,ncd7=-1;
    int nrb0=0,nrb1=0,nrb2=0,nrb3=0,nrb4=0,nrb5=0,nrb6=0,nrb7=0;
    int nre0=0,nre1=0,nre2=0,nre3=0,nre4=0,nre5=0,nre6=0,nre7=0;
    int nv0=-1,nv1=-1,nv2=-1,nv3=-1,nv4=-1,nv5=-1,nv6=-1,nv7=-1;

#define PF_ONE(i) \
    ncd##i = (nsl##i >= 0) ? (int)s_ord[nsl##i] : -1; \
    nrb##i = 0; nre##i = 0; \
    if (ncd##i >= 0) { nrb##i = s_roff[ncd##i]; nre##i = s_rend[ncd##i]; } \
    nv##i = (ncd##i >= 0 && nrb##i + ln < nre##i) ? OTH[nrb##i + ln] : -1;

#define PREFETCH_OCTET() do { \
    lo = ~s_visbits[ln]; hi = ~s_visbits[ln + 64]; \
    nsl0 = extract(); nsl1 = extract(); nsl2 = extract(); nsl3 = extract(); \
    nsl4 = extract(); nsl5 = extract(); nsl6 = extract(); nsl7 = extract(); \
    { int ms = (ln==0)?nsl0:(ln==1)?nsl1:(ln==2)?nsl2:(ln==3)?nsl3: \
               (ln==4)?nsl4:(ln==5)?nsl5:(ln==6)?nsl6:nsl7; \
      if (ln < 8 && ms >= 0) atomicOr(&s_visbits[ms >> 5], 1u << (ms & 31)); } \
    PF_ONE(0) PF_ONE(1) PF_ONE(2) PF_ONE(3) PF_ONE(4) PF_ONE(5) PF_ONE(6) PF_ONE(7) \
} while (0)

    // per-candidate proc: fresh absorption check + row-label gather, then dedup+commit
#define DO_CAND(CC, SLI, RBI, REI, VI) \
    if (CC >= 0) { \
        unsigned mm = s_meta[CC]; \
        unsigned gg = (VI >= 0) ? s_meta[VI] : 0u; \
        if ((int)(mm & 0x7FFFu) == CC) { \
            if (ln == 0) { \
                s_meta[CC] = ((unsigned)SLI << 16) | (unsigned)CC | 0x8000u; \
                s_so[k] = (unsigned short)CC; \
            } \
            int begin = nc; \
            if (REI - RBI <= 64) procFast(CC, SLI, VI, gg); \
            else                 procSlow(CC, SLI, RBI, REI, VI); \
            if (ln == 0) s_cnt[k] = nc - begin; \
            k++; \
        } \
    }

    PREFETCH_OCTET();   // octet 0
    for (;;) {
        // rotate prefetched octet into current (all named scalars)
        int c0=ncd0,c1=ncd1,c2=ncd2,c3=ncd3,c4=ncd4,c5=ncd5,c6=ncd6,c7=ncd7;
        int t0=nsl0,t1=nsl1,t2=nsl2,t3=nsl3,t4=nsl4,t5=nsl5,t6=nsl6,t7=nsl7;
        int a0=nrb0,a1=nrb1,a2=nrb2,a3=nrb3,a4=nrb4,a5=nrb5,a6=nrb6,a7=nrb7;
        int e0=nre0,e1=nre1,e2=nre2,e3=nre3,e4=nre4,e5=nre5,e6=nre6,e7=nre7;
        int v0=nv0,v1=nv1,v2=nv2,v3=nv3,v4=nv4,v5=nv5,v6=nv6,v7=nv7;
        if (c0 < 0) break;                 // visits only grow: empty stays empty
        PREFETCH_OCTET();                  // octet n+1 issues now; hides under procs
        DO_CAND(c0, t0, a0, e0, v0);
        DO_CAND(c1, t1, a1, e1, v1);
        DO_CAND(c2, t2, a2, e2, v2);
        DO_CAND(c3, t3, a3, e3, v3);
        DO_CAND(c4, t4, a4, e4, v4);
        DO_CAND(c5, t5, a5, e5, v5);
        DO_CAND(c6, t6, a6, e6, v6);
        DO_CAND(c7, t7, a7, e7, v7);
    }
#undef DO_CAND
#undef PREFETCH_OCTET
#undef PF_ONE
    const int K = k;

    // ---- rank of selected nodes among sorted(select); store into s_stamp ----
    // n selected  <=>  meta low id == n AND selbit set
    {
        int base = 0;
        for (int c = 0; c < NNODES / 64; ++c) {
            int n = c * 64 + ln;
            unsigned mv = s_meta[n];
            int f = ((mv & 0x8000u) != 0u) && ((int)(mv & 0x7FFFu) == n);
            unsigned long long b = __ballot(f);
            s_stamp[n] = base + __popcll(b & ltm);
            base += __popcll(b);
        }
    }
    // ---- SEL / CNTS / NST (exclusive prefix of CNTS) ----
    {
        int nb = 0;
        for (int c = 0; c * 64 < K; ++c) {
            int i = c * 64 + ln;
            int cv = (i < K) ? s_cnt[i] : 0;
            int x = cv;
#pragma unroll
            for (int off = 1; off < 64; off <<= 1) {
                int t = __shfl_up(x, off, 64);
                if (ln >= off) x += t;
            }
            if (i < K) { NST[i] = nb + x - cv; CNTS[i] = cv; SEL[i] = (int)s_so[i]; }
            nb += __shfl(x, 63, 64);
        }
    }
    // ---- FIL forward-fill via ballot + clz ----
    {
        int carry = 0;
        for (int c = 0; c * 64 < K; ++c) {
            int i = c * 64 + ln;
            int f = (i < K) && (s_cnt[i] > 0);
            unsigned long long b = __ballot(f);
            unsigned long long m = b & ((ln == 63) ? ~0ull : ((1ull << (ln + 1)) - 1ull));
            int fil = m ? (c * 64 + 63 - __clzll(m)) : carry;
            if (i < K) FIL[i] = fil;
            carry = b ? (c * 64 + 63 - __clzll(b)) : carry;
        }
    }
    if (ln == 0) SC[0] = K;
    // ---- dump labels + ranks for A3 ----
    for (int i = ln; i < NNODES; i += 64) {
        LABG[i] = (int)(s_meta[i] & 0x7FFFu);
        RNKG[i] = s_stamp[i];
    }
}

// ================= Phase A3: final arc compaction + remap (NT=1024) =================
__global__ __launch_bounds__(NT, 1)
void phaseA3(const int* __restrict__ U, const int* __restrict__ V,
             const int* __restrict__ LABG, const int* __restrict__ RNKG,
             const int* __restrict__ HAND, int* __restrict__ SC,
             int* __restrict__ TMP, float* __restrict__ out)
{
    __shared__ unsigned short l_lab[NNODES];
    __shared__ int l_rnk[NNODES];
    __shared__ int s_w[16];
    __shared__ int s_base[1];

    const int tid = threadIdx.x;
    for (int i = tid; i < NNODES; i += NT) {
        l_lab[i] = (unsigned short)LABG[i];
        l_rnk[i] = RNKG[i];
    }
    if (tid == 0) s_base[0] = 0;
    __syncthreads();

    const int E1 = HAND[0];
    const int K  = SC[0];
    const size_t obase = (size_t)K * 8192;

    // single-pass ordered compaction: 64 arcs/thread bitmask + one block scan
    for (int t0 = 0; t0 < E1; t0 += NT * 64) {
        unsigned long long fm = 0ull;
        const int base = t0 + tid * 64;
        if (base + 64 <= E1) {                   // vectorized int4 loads
            const int4* U4 = (const int4*)(U + base);
            const int4* V4 = (const int4*)(V + base);
#pragma unroll
            for (int q = 0; q < 16; ++q) {
                int4 a = U4[q], b = V4[q];
                int j = q * 4;
                if ((int)l_lab[a.x] != (int)l_lab[b.x]) fm |= 1ull << j;
                if ((int)l_lab[a.y] != (int)l_lab[b.y]) fm |= 1ull << (j + 1);
                if ((int)l_lab[a.z] != (int)l_lab[b.z]) fm |= 1ull << (j + 2);
                if ((int)l_lab[a.w] != (int)l_lab[b.w]) fm |= 1ull << (j + 3);
            }
        } else {
            for (int j = 0; j < 64; ++j) {
                int e = base + j;
                if (e < E1) {
                    if ((int)l_lab[U[e]] != (int)l_lab[V[e]]) fm |= 1ull << j;
                }
            }
        }
        int tot;
        int off = blockScanExcl(__popcll(fm), s_w, &tot);
        int r = s_base[0] + off;
        unsigned long long m = fm;
        while (m) {
            int j = __ffsll((long long)m) - 1; m &= m - 1;
            int e = base + j;
            out[obase + (size_t)r] = (float)l_rnk[(int)l_lab[U[e]]];
            TMP[r] = l_rnk[(int)l_lab[V[e]]];
            ++r;
        }
        __syncthreads();
        if (tid == 0) s_base[0] += tot;
        __syncthreads();
    }
    const int Ef = s_base[0];
    if (tid == 0) SC[1] = Ef;
    for (int r = tid; r < Ef; r += NT)
        out[obase + (size_t)Ef + (size_t)r] = (float)TMP[r];
}

// ---------------- Phase B: END rows (Dv | mean) with fill indirection ----------------
__global__ __launch_bounds__(256, 4)
void phaseB(const float* __restrict__ x,
            const float* __restrict__ W1, const float* __restrict__ W2,
            const float* __restrict__ B1, const float* __restrict__ B2,
            const int* __restrict__ NBR, const int* __restrict__ SEL,
            const int* __restrict__ CNTS, const int* __restrict__ NST,
            const int* __restrict__ FIL, const int* __restrict__ SC,
            float* __restrict__ out)
{
    const int K = SC[0];
    const int k = blockIdx.x;
    if (k >= K) return;
    const int kk   = FIL[k];
    const int node = SEL[kk];
    const int cnt  = CNTS[kk];
    const int st   = NST[kk];
    const int tid  = threadIdx.x;
    const float4* x4 = (const float4*)x;

    float4 acc[4];
#pragma unroll
    for (int j = 0; j < 4; j++) acc[j] = make_float4(0.f, 0.f, 0.f, 0.f);

    for (int r = 0; r < cnt; ++r) {
        const float4* row = x4 + (size_t)NBR[st + r] * 1024;
#pragma unroll
        for (int j = 0; j < 4; j++) {
            float4 t = row[tid + j * 256];
            acc[j].x += t.x; acc[j].y += t.y; acc[j].z += t.z; acc[j].w += t.w;
        }
    }

    const float fc  = (float)cnt;
    const float inv = 1.0f / (float)(cnt > 1 ? cnt : 1);
    const float4* xr = x4 + (size_t)node * 1024;
    float4* o4 = (float4*)(out + (size_t)k * 8192);

#pragma unroll
    for (int j = 0; j < 4; j++) {
        int c = tid + j * 256;
        float4 w1 = ((const float4*)W1)[c], b1 = ((const float4*)B1)[c];
        float4 w2 = ((const float4*)W2)[c], b2 = ((const float4*)B2)[c];
        float4 xv = xr[c];
        float4 pd, pm;
        pd.x = xv.x * w2.x + b2.x;
        pd.y = xv.y * w2.y + b2.y;
        pd.z = xv.z * w2.z + b2.z;
        pd.w = xv.w * w2.w + b2.w;
        pm.x = (acc[j].x * w1.x + fc * b1.x) * inv;
        pm.y = (acc[j].y * w1.y + fc * b1.y) * inv;
        pm.z = (acc[j].z * w1.z + fc * b1.z) * inv;
        pm.w = (acc[j].w * w1.w + fc * b1.w) * inv;
        o4[c] = pd;
        o4[1024 + c] = pm;
    }
}

extern "C" void kernel_launch(void* const* d_in, const int* in_sizes, int n_in,
                              void* d_out, int out_size, void* d_ws, size_t ws_size,
                              hipStream_t stream)
{
    const float* x  = (const float*)d_in[0];
    const int*   ei = (const int*)d_in[1];
    const float* W1 = (const float*)d_in[2];
    const float* W2 = (const float*)d_in[3];
    const float* B1 = (const float*)d_in[4];
    const float* B2 = (const float*)d_in[5];
    const int E0 = in_sizes[1] / 2;

    char* w = (char*)d_ws;
    int* U = (int*)w;                         // [ECAP]
    int* V = U + ECAP;                        // [ECAP]
    unsigned int* BM = (unsigned int*)(V + ECAP);   // 2 MB bitmap (iter-0 only)
    int* OTH = (int*)BM;                      // [2*ECAP] static CSR other-endpoint
    int* NBR = OTH + 2 * ECAP;                // [2*ECAP]
    int* TMP = NBR + 2 * ECAP;                // [2*ECAP] A3 scratch
    char* meta = (char*)BM + (2u << 20);
    int* SEL   = (int*)meta;
    int* CNTS  = SEL  + NNODES;
    int* NST   = CNTS + NNODES;
    int* FIL   = NST  + NNODES;
    int* SC    = FIL  + NNODES;               // [16]
    int* ORDV  = SC   + 16;
    int* ROFFG = ORDV + NNODES;
    int* RENDG = ROFFG + NNODES;
    int* LABG  = RENDG + NNODES;
    int* RNKG  = LABG + NNODES;
    int* HAND  = RNKG + NNODES;               // [16]
    float* out = (float*)d_out;

    // grid-parallel zero of the 2MB BM bitmap (plain kernel; graph-capture-safe)
    hipLaunchKernelGGL(zeroBM, dim3(512), dim3(256), 0, stream, (int4*)BM);

    hipLaunchKernelGGL(phaseA1, dim3(1), dim3(NT), 0, stream,
                       ei, E0, U, V, BM, NBR, OTH, ORDV, ROFFG, RENDG, HAND);
    hipLaunchKernelGGL(phaseA2, dim3(1), dim3(64), 0, stream,
                       OTH, NBR, ORDV, ROFFG, RENDG, HAND,
                       SEL, CNTS, NST, FIL, SC, LABG, RNKG);
    hipLaunchKernelGGL(phaseA3, dim3(1), dim3(NT), 0, stream,
                       U, V, LABG, RNKG, HAND, SC, TMP, out);
    hipLaunchKernelGGL(phaseB, dim3(NNODES), dim3(256), 0, stream,
                       x, W1, W2, B1, B2, NBR, SEL, CNTS, NST, FIL, SC, out);
}

// Round 7
// 1012.128 us; speedup vs baseline: 1.0304x; 1.0304x over previous
//
#include <hip/hip_runtime.h>
#include <hip/hip_bf16.h>

#define NT 1024
#define NNODES 4096
#define ECAP 65536   // max arcs after iteration-1 symmetrization (E0 <= 32768)

// ---------------- grid-parallel 2MB bitmap zero (replaces hipMemsetAsync) ----------------
__global__ __launch_bounds__(256)
void zeroBM(int4* __restrict__ bm) {
    bm[(size_t)blockIdx.x * 256 + threadIdx.x] = make_int4(0, 0, 0, 0);
}

// ---------------- block-wide exclusive scan over NT=1024 values ----------------
__device__ __forceinline__ int blockScanExcl(int v, int* s_w, int* total) {
    const int tid  = threadIdx.x;
    const int lane = tid & 63;
    const int wv   = tid >> 6;
    int x = v;
#pragma unroll
    for (int off = 1; off < 64; off <<= 1) {
        int t = __shfl_up(x, off, 64);
        if (lane >= off) x += t;
    }
    if (lane == 63) s_w[wv] = x;
    __syncthreads();
    if (tid < 16) {
        int y = s_w[tid];
#pragma unroll
        for (int off = 1; off < 16; off <<= 1) {
            int t = __shfl_up(y, off, 16);
            if (tid >= off) y += t;
        }
        s_w[tid] = y;
    }
    __syncthreads();
    int base = wv ? s_w[wv - 1] : 0;
    int tot  = s_w[15];
    __syncthreads();   // protect s_w reuse
    *total = tot;
    return base + x - v;   // exclusive prefix
}

// ================= Phase A1: preamble (R4-exact), dump handoff state =================
// s_bc slots: 0=node 2=nbrCnt 4=orderBase 5=appendBase 7=maxdeg 9=not64
__global__ __launch_bounds__(NT, 1)
void phaseA1(const int* __restrict__ ei, int E0,
             int* __restrict__ U, int* __restrict__ V,
             unsigned int* __restrict__ BM,
             int* __restrict__ NBR, int* __restrict__ OTH,
             int* __restrict__ ORDV, int* __restrict__ ROFFG, int* __restrict__ RENDG,
             int* __restrict__ HAND)
{
    __shared__ unsigned short s_order[NNODES];
    __shared__ unsigned char  s_vis[NNODES];
    __shared__ unsigned char  s_rank[NNODES];     // counting-sort within-group rank
    __shared__ unsigned int   s_hb[NNODES / 32];
    __shared__ int s_roff[NNODES];
    __shared__ int s_rend[NNODES];
    __shared__ int s_tmp[NNODES];
    __shared__ int s_mat[64][65];                 // [deg][group] counts / prefixes; col 64 = desc base
    __shared__ int s_w[16];
    __shared__ int s_bc[16];

    const int tid = threadIdx.x;

    for (int i = tid; i < NNODES; i += NT) { s_vis[i] = 0; s_tmp[i] = 0; }
    for (int i = tid; i < NNODES / 32; i += NT) s_hb[i] = 0;
    if (tid < 16) s_bc[tid] = 0;
    __syncthreads();

    // ---- detect int64 vs int32 edge buffer ----
    for (int i = tid; i < E0; i += NT)
        if (ei[2 * i + 1] != 0) s_bc[9] = 1;
    __syncthreads();
    const int is64 = !s_bc[9];

    // ---- copy edges + degree histogram (I+O) ----
    for (int e = tid; e < E0; e += NT) {
        int uu = ei[is64 ? 2 * e : e];
        int vv = ei[is64 ? 2 * (E0 + e) : (E0 + e)];
        U[e] = uu; V[e] = vv;
        atomicAdd(&s_tmp[uu], 1);
        atomicAdd(&s_tmp[vv], 1);
    }
    __syncthreads();
    for (int n = tid; n < NNODES; n += NT) atomicMax(&s_bc[7], s_tmp[n]);
    __syncthreads();
    const int maxd = s_bc[7];

    // ---- stable argsort by descending degree ----
    if (maxd < 64) {
        // fast path: stable counting sort, ~5 barriers total.
        const int wv = tid >> 6, lane = tid & 63;
        const unsigned long long ltm = (1ull << lane) - 1ull;
        for (int g = wv; g < 64; g += 16) {
            int n = g * 64 + lane;
            int d = s_tmp[n];
            int rk = 0;
            for (int dd = 0; dd < 64; ++dd) {
                unsigned long long bal = __ballot(d == dd);
                if (lane == 0) s_mat[dd][g] = __popcll(bal);
                if (d == dd) rk = __popcll(bal & ltm);
            }
            s_rank[n] = (unsigned char)rk;
        }
        __syncthreads();
        if (tid < 64) {                      // per-degree prefix across the 64 id-groups
            int run = 0;
            for (int g = 0; g < 64; ++g) { int t = s_mat[tid][g]; s_mat[tid][g] = run; run += t; }
            s_mat[tid][64] = run;            // total per degree
        }
        __syncthreads();
        if (tid < 64) {                      // descending-degree exclusive base
            int x = s_mat[tid][64];
#pragma unroll
            for (int off = 1; off < 64; off <<= 1) {
                int t = __shfl_up(x, off, 64);
                if (tid >= off) x += t;
            }
            int T = __shfl(x, 63, 64);
            s_mat[tid][64] = T - x;          // sum of bins with degree > tid
        }
        __syncthreads();
        for (int g = wv; g < 64; g += 16) {
            int n = g * 64 + lane;
            int d = s_tmp[n];
            int pos = s_mat[d][64] + s_mat[d][g] + (int)s_rank[n];
            s_order[pos] = (unsigned short)n;
        }
        __syncthreads();
    } else {
        // legacy fallback (exact, slow): one scan round per degree value
        for (int d = maxd; d >= 0; --d) {
            int n0 = tid * 4;
            int f0 = (s_tmp[n0] == d), f1 = (s_tmp[n0 + 1] == d);
            int f2 = (s_tmp[n0 + 2] == d), f3 = (s_tmp[n0 + 3] == d);
            int tot;
            int off = blockScanExcl(f0 + f1 + f2 + f3, s_w, &tot);
            int idx = s_bc[4] + off;
            if (f0) s_order[idx++] = (unsigned short)n0;
            if (f1) s_order[idx++] = (unsigned short)(n0 + 1);
            if (f2) s_order[idx++] = (unsigned short)(n0 + 2);
            if (f3) s_order[idx++] = (unsigned short)(n0 + 3);
            __syncthreads();
            if (tid == 0) s_bc[4] += tot;
            __syncthreads();
        }
    }

    // ---- iteration 0 (full-array scans, eager relabel) ----
    if (tid == 0) {
        int nd = s_order[0];
        s_bc[0] = nd; s_vis[nd] = 1;
    }
    __syncthreads();
    {
        const int node = s_bc[0];
        for (int e = tid; e < E0; e += NT) {
            int uu = U[e], vv = V[e];
            if (uu == node) {
                int w = vv; unsigned m = 1u << (w & 31);
                unsigned old = atomicOr(&s_hb[w >> 5], m);
                if (!(old & m)) { int i = atomicAdd(&s_bc[2], 1); s_tmp[i] = w; s_vis[w] = 1; }
            }
            if (vv == node) {
                int w = uu; unsigned m = 1u << (w & 31);
                unsigned old = atomicOr(&s_hb[w >> 5], m);
                if (!(old & m)) { int i = atomicAdd(&s_bc[2], 1); s_tmp[i] = w; s_vis[w] = 1; }
            }
        }
        __syncthreads();
        // eager relabel Hn = H \ {node} (U/V frozen afterwards)
        for (int e = tid; e < E0; e += NT) {
            int uu = U[e];
            if (uu != node && ((s_hb[uu >> 5] >> (uu & 31)) & 1)) U[e] = node;
            int vv = V[e];
            if (vv != node && ((s_hb[vv >> 5] >> (vv & 31)) & 1)) V[e] = node;
        }
        __syncthreads();
    }

    // ---- symmetry append (only iteration ever needing it) ----
    // BM is pre-zeroed by the grid-parallel zeroBM kernel on the stream.
    for (int e = tid; e < E0; e += NT) {
        int uu = U[e], vv = V[e];
        if (uu != vv) {
            unsigned code = ((unsigned)uu << 12) | (unsigned)vv;
            atomicOr(&BM[code >> 5], 1u << (code & 31));
        }
    }
    __syncthreads();
    // single-pass ordered compaction: 32 arcs/thread bitmask + one block scan per 32K chunk
    for (int t0 = 0; t0 < E0; t0 += NT * 32) {
        unsigned fm = 0u;
        const int base = t0 + tid * 32;
        for (int j = 0; j < 32; ++j) {
            int e = base + j;
            if (e < E0) {
                int uu = U[e], vv = V[e];
                if (uu != vv) {
                    unsigned rc = ((unsigned)vv << 12) | (unsigned)uu;
                    unsigned old = atomicOr(&BM[rc >> 5], 0u);   // L2 read
                    if (!((old >> (rc & 31)) & 1u)) fm |= (1u << j);
                }
            }
        }
        int tot;
        int off = blockScanExcl(__popc(fm), s_w, &tot);
        int r = s_bc[5] + off;
        unsigned m = fm;
        while (m) {
            int j = __ffs((int)m) - 1; m &= m - 1;
            int e = base + j;
            U[E0 + r] = V[e]; V[E0 + r] = U[e];
            ++r;
        }
        __syncthreads();
        if (tid == 0) s_bc[5] += tot;
        __syncthreads();
    }
    const int E1 = E0 + s_bc[5];

    // ---- build static CSR, OUT-endpoint only ----
    for (int n = tid; n < NNODES; n += NT) s_roff[n] = 0;
    __syncthreads();
    for (int e = tid; e < E1; e += NT) {
        int uu = U[e], vv = V[e];
        if (uu != vv) atomicAdd(&s_roff[uu], 1);
    }
    __syncthreads();
    {
        int n0 = tid * 4;
        int c0 = s_roff[n0], c1 = s_roff[n0 + 1], c2 = s_roff[n0 + 2], c3 = s_roff[n0 + 3];
        int tot;
        int off = blockScanExcl(c0 + c1 + c2 + c3, s_w, &tot);
        int st = off;
        s_roff[n0] = st;     s_rend[n0] = st;     st += c0;
        s_roff[n0 + 1] = st; s_rend[n0 + 1] = st; st += c1;
        s_roff[n0 + 2] = st; s_rend[n0 + 2] = st; st += c2;
        s_roff[n0 + 3] = st; s_rend[n0 + 3] = st;
    }
    __syncthreads();
    for (int e = tid; e < E1; e += NT) {
        int uu = U[e], vv = V[e];
        if (uu != vv) {
            int p = atomicAdd(&s_rend[uu], 1);
            OTH[p] = vv;
        }
    }
    __syncthreads();
    {   // flush iter-0 staged H into global NBR
        const int cnt0 = s_bc[2];
        for (int i = tid; i < cnt0; i += NT) NBR[i] = s_tmp[i];
    }
    // ---- dump handoff state ----
    for (int i = tid; i < NNODES; i += NT) {
        int nd = (int)s_order[i];
        ORDV[i]  = nd | (s_vis[nd] ? 0x8000 : 0);
        ROFFG[i] = s_roff[i];
        RENDG[i] = s_rend[i];
    }
    if (tid == 0) { HAND[0] = E1; HAND[1] = s_bc[2]; HAND[2] = s_bc[0]; }
}

// ================= Phase A2: main loop, SINGLE WAVE, zero barriers =================
// PAIR-PACKED processing: two hubs share one proc chain (row A in lanes 0-31,
// row B in lanes 32-63) — one meta gather, one vstamp dedup, one ballot, one
// commit for both. Exactness restored by a conflict detector based on the label
// invariant (labels point only to {self} U {selected hubs}; an unselected
// gathered value w always has w == o):
//   - same value w in both halves  <=> vstamp winner in other half ((r^ln)&32)
//   - B absorbed by A              <=> w == CB seen in half 0
// w == CA in half 1 is LEGIT (reference H_B may contain selected A) and commits
// normally. On conflict (~6% of pairs): solo-A on its half, fresh recheck of B,
// solo-B. Rows > 32 (rare, early hubs) take a full-width solo with epoch dedup.
// Octet front-end (8 candidates per snapshot) amortizes extraction; NO
// cross-octet prefetch (round-6 FETCH waste). Premark keeps extraction monotone;
// per-candidate freshness check (s_meta[c]&0x7FFF)==c drops absorbed candidates.
__global__ __launch_bounds__(64, 1)
void phaseA2(const int* __restrict__ OTH, int* __restrict__ NBR,
             const int* __restrict__ ORDV, const int* __restrict__ ROFFG,
             const int* __restrict__ RENDG, const int* __restrict__ HAND,
             int* __restrict__ SEL, int* __restrict__ CNTS,
             int* __restrict__ NST, int* __restrict__ FIL, int* __restrict__ SC,
             int* __restrict__ LABG, int* __restrict__ RNKG)
{
    __shared__ unsigned short s_ord[NNODES];          // order slot -> node id
    __shared__ unsigned int   s_visbits[NNODES / 32]; // visited bit per ORDER SLOT
    __shared__ unsigned int   s_meta[NNODES];         // fused label/slot/sel word
    __shared__ unsigned short s_so[NNODES];           // selection order of hubs
    __shared__ int s_cnt[NNODES];                     // per-iteration |H_k|
    __shared__ int s_stamp[NNODES];                   // dedup scratch; reused as rank
    __shared__ int s_roff[NNODES];
    __shared__ int s_rend[NNODES];

    const int ln = threadIdx.x;                   // single wave: tid == lane
    const unsigned long long ltm = (1ull << ln) - 1ull;
    const int half  = ln >> 5;                    // 0: row A lanes, 1: row B lanes
    const int hlane = ln & 31;
    const int cnt0 = HAND[1], hub0 = HAND[2];
    volatile int* vstamp = s_stamp;               // blocks store->load forwarding

    for (int i = ln; i < NNODES / 32; i += 64) s_visbits[i] = 0u;
    for (int i = ln; i < NNODES; i += 64) {
        int ov = ORDV[i];
        int nd = ov & 0x7FFF;
        s_ord[i] = (unsigned short)nd;
        s_meta[nd] = ((unsigned)i << 16) | (unsigned)nd;   // slot | id, unselected
        s_roff[i] = ROFFG[i];
        s_rend[i] = RENDG[i];
        s_stamp[i] = 0; s_cnt[i] = 0;
        if (ov & 0x8000) atomicOr(&s_visbits[i >> 5], 1u << (i & 31));
    }
    if (ln == 0) {
        s_meta[hub0] = (unsigned)hub0 | 0x8000u;   // slot 0 | id | selected
        s_so[0] = (unsigned short)hub0;
        s_cnt[0] = cnt0;
    }
    // single wave: instruction order + lgkmcnt waits give LDS visibility; no barrier.

    int nc = cnt0;   // NBR cursor, wave-uniform register
    int k = 1;

    // register-resident bitmask extraction: lane ln holds words {ln, ln+64}
    unsigned lo = 0u, hi = 0u;
    auto extract = [&]() -> int {
        unsigned long long b = __ballot(lo != 0u);
        if (b) {
            int sl = __ffsll((long long)b) - 1;
            unsigned ww = __shfl(lo, sl, 64);
            if (ln == sl) lo &= lo - 1;
            return sl * 32 + (__ffs((int)ww) - 1);
        }
        b = __ballot(hi != 0u);
        if (b) {
            int sl = __ffsll((long long)b) - 1;
            unsigned ww = __shfl(hi, sl, 64);
            if (ln == sl) hi &= hi - 1;
            return 2048 + sl * 32 + (__ffs((int)ww) - 1);
        }
        return -1;
    };

    // solo proc over this pair's PRELOADED half data (len <= 32)
    auto soloHalf = [&](int C, int S, int HALF, int PV) {
        const unsigned relv = ((unsigned)S << 16) | (unsigned)C | 0x8000u;
        if (ln == 0) s_meta[C] = relv;               // select BEFORE gather
        bool lv = (PV >= 0) && (half == HALF);
        unsigned g = lv ? s_meta[PV] : 0u;           // fresh gather (sees prior relabels)
        int w = lv ? (int)(g & 0x7FFFu) : C;
        bool cnd = lv && (w != C);
        if (cnd) vstamp[w] = ln;
        int r = cnd ? vstamp[w] : -1;
        bool nw = cnd && (r == ln);
        unsigned long long bal = __ballot(nw);
        if (nw) {
            NBR[nc + __popcll(bal & ltm)] = w;
            int slot = (int)(g >> 16);
            atomicOr(&s_visbits[slot >> 5], 1u << (slot & 31));
            if (!(g & 0x8000u)) s_meta[w] = relv;
        }
        int cnt = (int)__popcll(bal);
        if (ln == 0) { s_so[k] = (unsigned short)C; s_cnt[k] = cnt; }
        nc += cnt; k++;
    };

    // solo proc with fresh full-width loads (rare: len > 32), epoch dedup k<<6
    // (vstamp lane-id residues < 64 <= k<<6 never alias an epoch; old epochs < key)
    auto soloFull = [&](int C, int S, int RB, int RE) {
        const unsigned relv = ((unsigned)S << 16) | (unsigned)C | 0x8000u;
        if (ln == 0) s_meta[C] = relv;
        const int key = k << 6;
        int begin = nc;
        for (int s0 = RB; s0 < RE; s0 += 64) {
            int o = (s0 + ln < RE) ? OTH[s0 + ln] : -1;
            unsigned g = (o >= 0) ? s_meta[o] : 0u;
            int w = (o >= 0) ? (int)(g & 0x7FFFu) : C;
            bool cnd = (w != C);
            int old = key;
            if (cnd) old = atomicMax(&s_stamp[w], key);
            bool nw = cnd && (old < key);
            unsigned long long bal = __ballot(nw);
            if (nw) {
                NBR[nc + __popcll(bal & ltm)] = w;
                int slot = (int)(g >> 16);
                atomicOr(&s_visbits[slot >> 5], 1u << (slot & 31));
                if (!(g & 0x8000u)) s_meta[w] = relv;
            }
            nc += (int)__popcll(bal);
        }
        if (ln == 0) { s_so[k] = (unsigned short)C; s_cnt[k] = nc - begin; }
        k++;
    };

    auto doPair = [&](int CA, int SA, int RBA, int REA,
                      int CB, int SB, int RBB, int REB, int PV) {
        if (CA < 0 && CB < 0) return;
        bool okA = (CA >= 0) && ((int)(s_meta[CA] & 0x7FFFu) == CA);   // fresh
        bool okB = (CB >= 0) && ((int)(s_meta[CB] & 0x7FFFu) == CB);
        int lenA = (CA >= 0) ? (REA - RBA) : 0;
        int lenB = (CB >= 0) ? (REB - RBB) : 0;
        if (okA && okB && lenA <= 32 && lenB <= 32) {
            const unsigned relvA = ((unsigned)SA << 16) | (unsigned)CA | 0x8000u;
            const unsigned relvB = ((unsigned)SB << 16) | (unsigned)CB | 0x8000u;
            if (ln == 0) s_meta[CA] = relvA;         // A selected pre-gather; B DEFERRED
            unsigned g = (PV >= 0) ? s_meta[PV] : 0u;
            int hub = (half == 0) ? CA : CB;
            int w = (PV >= 0) ? (int)(g & 0x7FFFu) : hub;
            bool valid = (PV >= 0) && (w != hub);
            if (valid) vstamp[w] = ln;
            int r = valid ? vstamp[w] : -1;
            bool bad = (valid && (((r ^ ln) & 32) != 0)) ||      // w in both halves
                       (valid && half == 0 && w == CB);          // B absorbed by A
            if (__ballot(bad) == 0ull) {
                bool nw = valid && (r == ln);
                unsigned long long bal = __ballot(nw);
                if (nw) {
                    NBR[nc + __popcll(bal & ltm)] = w;           // A-half first, then B
                    int slot = (int)(g >> 16);
                    atomicOr(&s_visbits[slot >> 5], 1u << (slot & 31));
                    unsigned relv = (half == 0) ? relvA : relvB;
                    if (!(g & 0x8000u)) s_meta[w] = relv;
                }
                int cA = (int)__popcll(bal & 0xFFFFFFFFull);
                int cB = (int)__popcll(bal >> 32);
                if (ln == 0) {
                    s_meta[CB] = relvB;                          // select B now
                    s_so[k] = (unsigned short)CA;     s_cnt[k] = cA;
                    s_so[k + 1] = (unsigned short)CB; s_cnt[k + 1] = cB;
                }
                nc += cA + cB; k += 2;
                return;
            }
            // conflict: sequential exact — A solo on its half, fresh recheck B
            soloHalf(CA, SA, 0, PV);
            if ((int)(s_meta[CB] & 0x7FFFu) == CB) soloHalf(CB, SB, 1, PV);
            return;
        }
        // rare / degraded path: sequential solos with fresh checks
        if (okA) {
            if (lenA <= 32) soloHalf(CA, SA, 0, PV);
            else            soloFull(CA, SA, RBA, REA);
        }
        if (CB >= 0 && (int)(s_meta[CB] & 0x7FFFu) == CB) {
            if (lenB <= 32) soloHalf(CB, SB, 1, PV);
            else            soloFull(CB, SB, RBB, REB);
        }
    };

    for (;;) {
        // ---- octet front-end: extract 8 candidates from one snapshot ----
        lo = ~s_visbits[ln]; hi = ~s_visbits[ln + 64];
        int sl0 = extract(); int sl1 = extract(); int sl2 = extract(); int sl3 = extract();
        int sl4 = extract(); int sl5 = extract(); int sl6 = extract(); int sl7 = extract();
        if (sl0 < 0) break;
        {   // premark all candidates (monotone extraction; absorption via meta check)
            int ms = (ln==0)?sl0:(ln==1)?sl1:(ln==2)?sl2:(ln==3)?sl3:
                     (ln==4)?sl4:(ln==5)?sl5:(ln==6)?sl6:sl7;
            if (ln < 8 && ms >= 0) atomicOr(&s_visbits[ms >> 5], 1u << (ms & 31));
        }
        int c0 = (sl0>=0)?(int)s_ord[sl0]:-1; int c1 = (sl1>=0)?(int)s_ord[sl1]:-1;
        int c2 = (sl2>=0)?(int)s_ord[sl2]:-1; int c3 = (sl3>=0)?(int)s_ord[sl3]:-1;
        int c4 = (sl4>=0)?(int)s_ord[sl4]:-1; int c5 = (sl5>=0)?(int)s_ord[sl5]:-1;
        int c6 = (sl6>=0)?(int)s_ord[sl6]:-1; int c7 = (sl7>=0)?(int)s_ord[sl7]:-1;

        int rb0=0,re0=0,rb1=0,re1=0,rb2=0,re2=0,rb3=0,re3=0;
        int rb4=0,re4=0,rb5=0,re5=0,rb6=0,re6=0,rb7=0,re7=0;
        if (c0>=0){rb0=s_roff[c0];re0=s_rend[c0];} if (c1>=0){rb1=s_roff[c1];re1=s_rend[c1];}
        if (c2>=0){rb2=s_roff[c2];re2=s_rend[c2];} if (c3>=0){rb3=s_roff[c3];re3=s_rend[c3];}
        if (c4>=0){rb4=s_roff[c4];re4=s_rend[c4];} if (c5>=0){rb5=s_roff[c5];re5=s_rend[c5];}
        if (c6>=0){rb6=s_roff[c6];re6=s_rend[c6];} if (c7>=0){rb7=s_roff[c7];re7=s_rend[c7];}

        // ---- 4 packed pair-loads issue together -> one shared L2 wait ----
        int b0 = (half==0)?rb0:rb1, l0 = (half==0)?re0:re1; bool k0 = (half==0)?(c0>=0):(c1>=0);
        int b1 = (half==0)?rb2:rb3, l1 = (half==0)?re2:re3; bool k1 = (half==0)?(c2>=0):(c3>=0);
        int b2 = (half==0)?rb4:rb5, l2 = (half==0)?re4:re5; bool k2 = (half==0)?(c4>=0):(c5>=0);
        int b3 = (half==0)?rb6:rb7, l3 = (half==0)?re6:re7; bool k3 = (half==0)?(c6>=0):(c7>=0);
        int pv0 = (k0 && b0 + hlane < l0) ? OTH[b0 + hlane] : -1;
        int pv1 = (k1 && b1 + hlane < l1) ? OTH[b1 + hlane] : -1;
        int pv2 = (k2 && b2 + hlane < l2) ? OTH[b2 + hlane] : -1;
        int pv3 = (k3 && b3 + hlane < l3) ? OTH[b3 + hlane] : -1;

        doPair(c0, sl0, rb0, re0, c1, sl1, rb1, re1, pv0);
        doPair(c2, sl2, rb2, re2, c3, sl3, rb3, re3, pv1);
        doPair(c4, sl4, rb4, re4, c5, sl5, rb5, re5, pv2);
        doPair(c6, sl6, rb6, re6, c7, sl7, rb7, re7, pv3);
    }
    const int K = k;

    // ---- rank of selected nodes among sorted(select); store into s_stamp ----
    // n selected  <=>  meta low id == n AND selbit set
    {
        int base = 0;
        for (int c = 0; c < NNODES / 64; ++c) {
            int n = c * 64 + ln;
            unsigned mv = s_meta[n];
            int f = ((mv & 0x8000u) != 0u) && ((int)(mv & 0x7FFFu) == n);
            unsigned long long b = __ballot(f);
            s_stamp[n] = base + __popcll(b & ltm);
            base += __popcll(b);
        }
    }
    // ---- SEL / CNTS / NST (exclusive prefix of CNTS) ----
    {
        int nb = 0;
        for (int c = 0; c * 64 < K; ++c) {
            int i = c * 64 + ln;
            int cv = (i < K) ? s_cnt[i] : 0;
            int x = cv;
#pragma unroll
            for (int off = 1; off < 64; off <<= 1) {
                int t = __shfl_up(x, off, 64);
                if (ln >= off) x += t;
            }
            if (i < K) { NST[i] = nb + x - cv; CNTS[i] = cv; SEL[i] = (int)s_so[i]; }
            nb += __shfl(x, 63, 64);
        }
    }
    // ---- FIL forward-fill via ballot + clz ----
    {
        int carry = 0;
        for (int c = 0; c * 64 < K; ++c) {
            int i = c * 64 + ln;
            int f = (i < K) && (s_cnt[i] > 0);
            unsigned long long b = __ballot(f);
            unsigned long long m = b & ((ln == 63) ? ~0ull : ((1ull << (ln + 1)) - 1ull));
            int fil = m ? (c * 64 + 63 - __clzll(m)) : carry;
            if (i < K) FIL[i] = fil;
            carry = b ? (c * 64 + 63 - __clzll(b)) : carry;
        }
    }
    if (ln == 0) SC[0] = K;
    // ---- dump labels + ranks for A3 ----
    for (int i = ln; i < NNODES; i += 64) {
        LABG[i] = (int)(s_meta[i] & 0x7FFFu);
        RNKG[i] = s_stamp[i];
    }
}

// ================= Phase A3: final arc compaction + remap (NT=1024) =================
__global__ __launch_bounds__(NT, 1)
void phaseA3(const int* __restrict__ U, const int* __restrict__ V,
             const int* __restrict__ LABG, const int* __restrict__ RNKG,
             const int* __restrict__ HAND, int* __restrict__ SC,
             int* __restrict__ TMP, float* __restrict__ out)
{
    __shared__ unsigned short l_lab[NNODES];
    __shared__ int l_rnk[NNODES];
    __shared__ int s_w[16];
    __shared__ int s_base[1];

    const int tid = threadIdx.x;
    for (int i = tid; i < NNODES; i += NT) {
        l_lab[i] = (unsigned short)LABG[i];
        l_rnk[i] = RNKG[i];
    }
    if (tid == 0) s_base[0] = 0;
    __syncthreads();

    const int E1 = HAND[0];
    const int K  = SC[0];
    const size_t obase = (size_t)K * 8192;

    // single-pass ordered compaction: 64 arcs/thread bitmask + one block scan
    for (int t0 = 0; t0 < E1; t0 += NT * 64) {
        unsigned long long fm = 0ull;
        const int base = t0 + tid * 64;
        if (base + 64 <= E1) {                   // vectorized int4 loads
            const int4* U4 = (const int4*)(U + base);
            const int4* V4 = (const int4*)(V + base);
#pragma unroll
            for (int q = 0; q < 16; ++q) {
                int4 a = U4[q], b = V4[q];
                int j = q * 4;
                if ((int)l_lab[a.x] != (int)l_lab[b.x]) fm |= 1ull << j;
                if ((int)l_lab[a.y] != (int)l_lab[b.y]) fm |= 1ull << (j + 1);
                if ((int)l_lab[a.z] != (int)l_lab[b.z]) fm |= 1ull << (j + 2);
                if ((int)l_lab[a.w] != (int)l_lab[b.w]) fm |= 1ull << (j + 3);
            }
        } else {
            for (int j = 0; j < 64; ++j) {
                int e = base + j;
                if (e < E1) {
                    if ((int)l_lab[U[e]] != (int)l_lab[V[e]]) fm |= 1ull << j;
                }
            }
        }
        int tot;
        int off = blockScanExcl(__popcll(fm), s_w, &tot);
        int r = s_base[0] + off;
        unsigned long long m = fm;
        while (m) {
            int j = __ffsll((long long)m) - 1; m &= m - 1;
            int e = base + j;
            out[obase + (size_t)r] = (float)l_rnk[(int)l_lab[U[e]]];
            TMP[r] = l_rnk[(int)l_lab[V[e]]];
            ++r;
        }
        __syncthreads();
        if (tid == 0) s_base[0] += tot;
        __syncthreads();
    }
    const int Ef = s_base[0];
    if (tid == 0) SC[1] = Ef;
    for (int r = tid; r < Ef; r += NT)
        out[obase + (size_t)Ef + (size_t)r] = (float)TMP[r];
}

// ---------------- Phase B: END rows (Dv | mean) with fill indirection ----------------
__global__ __launch_bounds__(256, 4)
void phaseB(const float* __restrict__ x,
            const float* __restrict__ W1, const float* __restrict__ W2,
            const float* __restrict__ B1, const float* __restrict__ B2,
            const int* __restrict__ NBR, const int* __restrict__ SEL,
            const int* __restrict__ CNTS, const int* __restrict__ NST,
            const int* __restrict__ FIL, const int* __restrict__ SC,
            float* __restrict__ out)
{
    const int K = SC[0];
    const int k = blockIdx.x;
    if (k >= K) return;
    const int kk   = FIL[k];
    const int node = SEL[kk];
    const int cnt  = CNTS[kk];
    const int st   = NST[kk];
    const int tid  = threadIdx.x;
    const float4* x4 = (const float4*)x;

    float4 acc[4];
#pragma unroll
    for (int j = 0; j < 4; j++) acc[j] = make_float4(0.f, 0.f, 0.f, 0.f);

    for (int r = 0; r < cnt; ++r) {
        const float4* row = x4 + (size_t)NBR[st + r] * 1024;
#pragma unroll
        for (int j = 0; j < 4; j++) {
            float4 t = row[tid + j * 256];
            acc[j].x += t.x; acc[j].y += t.y; acc[j].z += t.z; acc[j].w += t.w;
        }
    }

    const float fc  = (float)cnt;
    const float inv = 1.0f / (float)(cnt > 1 ? cnt : 1);
    const float4* xr = x4 + (size_t)node * 1024;
    float4* o4 = (float4*)(out + (size_t)k * 8192);

#pragma unroll
    for (int j = 0; j < 4; j++) {
        int c = tid + j * 256;
        float4 w1 = ((const float4*)W1)[c], b1 = ((const float4*)B1)[c];
        float4 w2 = ((const float4*)W2)[c], b2 = ((const float4*)B2)[c];
        float4 xv = xr[c];
        float4 pd, pm;
        pd.x = xv.x * w2.x + b2.x;
        pd.y = xv.y * w2.y + b2.y;
        pd.z = xv.z * w2.z + b2.z;
        pd.w = xv.w * w2.w + b2.w;
        pm.x = (acc[j].x * w1.x + fc * b1.x) * inv;
        pm.y = (acc[j].y * w1.y + fc * b1.y) * inv;
        pm.z = (acc[j].z * w1.z + fc * b1.z) * inv;
        pm.w = (acc[j].w * w1.w + fc * b1.w) * inv;
        o4[c] = pd;
        o4[1024 + c] = pm;
    }
}

extern "C" void kernel_launch(void* const* d_in, const int* in_sizes, int n_in,
                              void* d_out, int out_size, void* d_ws, size_t ws_size,
                              hipStream_t stream)
{
    const float* x  = (const float*)d_in[0];
    const int*   ei = (const int*)d_in[1];
    const float* W1 = (const float*)d_in[2];
    const float* W2 = (const float*)d_in[3];
    const float* B1 = (const float*)d_in[4];
    const float* B2 = (const float*)d_in[5];
    const int E0 = in_sizes[1] / 2;

    char* w = (char*)d_ws;
    int* U = (int*)w;                         // [ECAP]
    int* V = U + ECAP;                        // [ECAP]
    unsigned int* BM = (unsigned int*)(V + ECAP);   // 2 MB bitmap (iter-0 only)
    int* OTH = (int*)BM;                      // [2*ECAP] static CSR other-endpoint
    int* NBR = OTH + 2 * ECAP;                // [2*ECAP]
    int* TMP = NBR + 2 * ECAP;                // [2*ECAP] A3 scratch
    char* meta = (char*)BM + (2u << 20);
    int* SEL   = (int*)meta;
    int* CNTS  = SEL  + NNODES;
    int* NST   = CNTS + NNODES;
    int* FIL   = NST  + NNODES;
    int* SC    = FIL  + NNODES;               // [16]
    int* ORDV  = SC   + 16;
    int* ROFFG = ORDV + NNODES;
    int* RENDG = ROFFG + NNODES;
    int* LABG  = RENDG + NNODES;
    int* RNKG  = LABG + NNODES;
    int* HAND  = RNKG + NNODES;               // [16]
    float* out = (float*)d_out;

    // grid-parallel zero of the 2MB BM bitmap (plain kernel; graph-capture-safe)
    hipLaunchKernelGGL(zeroBM, dim3(512), dim3(256), 0, stream, (int4*)BM);

    hipLaunchKernelGGL(phaseA1, dim3(1), dim3(NT), 0, stream,
                       ei, E0, U, V, BM, NBR, OTH, ORDV, ROFFG, RENDG, HAND);
    hipLaunchKernelGGL(phaseA2, dim3(1), dim3(64), 0, stream,
                       OTH, NBR, ORDV, ROFFG, RENDG, HAND,
                       SEL, CNTS, NST, FIL, SC, LABG, RNKG);
    hipLaunchKernelGGL(phaseA3, dim3(1), dim3(NT), 0, stream,
                       U, V, LABG, RNKG, HAND, SC, TMP, out);
    hipLaunchKernelGGL(phaseB, dim3(NNODES), dim3(256), 0, stream,
                       x, W1, W2, B1, B2, NBR, SEL, CNTS, NST, FIL, SC, out);
}